// Round 1
// baseline (265.474 us; speedup 1.0000x reference)
//
#include <hip/hip_runtime.h>
#include <math.h>

// Problem constants
#define B_  32
#define S_  2048
#define D_  512
#define A_  256

// ws layout (float offsets)
#define WEFF_OFF  0            // 256 floats
#define DEC_OFF   256          // B*A = 8192
#define EPART_OFF 8448         // 2 * B*S = 131072
#define CTX_OFF   139520       // 16 * B * D = 262144
// total 401664 floats = 1.57 MB

// ---------------------------------------------------------------------------
// weight-norm: weff[a] = v_g * v_w[a] / ||v_w||
__global__ void ma_weff_kernel(const float* __restrict__ v_w,
                               const float* __restrict__ v_g,
                               float* __restrict__ ws) {
    int t = threadIdx.x;                 // 256 threads
    float v = v_w[t];
    float sq = v * v;
    #pragma unroll
    for (int off = 32; off > 0; off >>= 1) sq += __shfl_down(sq, off, 64);
    __shared__ float red[4];
    if ((t & 63) == 0) red[t >> 6] = sq;
    __syncthreads();
    float n2 = red[0] + red[1] + red[2] + red[3];
    ws[WEFF_OFF + t] = v_g[0] * v / sqrtf(n2);
}

// ---------------------------------------------------------------------------
// dec_term[b][a] = dot(V[a,:], dec[b,0,:]) + bias[a]
__global__ void ma_decterm_kernel(const float* __restrict__ dec,
                                  const float* __restrict__ V,
                                  const float* __restrict__ bvec,
                                  float* __restrict__ ws) {
    __shared__ float dl[D_];
    int b = blockIdx.x, t = threadIdx.x;  // 256 threads, t == a
    dl[t]       = dec[b * D_ + t];
    dl[t + 256] = dec[b * D_ + 256 + t];
    __syncthreads();
    const float4* Vr = (const float4*)(V + (size_t)t * D_);
    float acc = 0.f;
    #pragma unroll 4
    for (int k = 0; k < D_ / 4; ++k) {
        float4 v4 = Vr[k];
        acc = fmaf(v4.x, dl[4*k+0], acc);
        acc = fmaf(v4.y, dl[4*k+1], acc);
        acc = fmaf(v4.z, dl[4*k+2], acc);
        acc = fmaf(v4.w, dl[4*k+3], acc);
    }
    ws[DEC_OFF + b * A_ + t] = acc + bvec[t];
}

// ---------------------------------------------------------------------------
// Energy GEMM: epart[nch][row] = sum_{a in chunk} tanh(enc@W^T + dec_term) * weff
// Tile: BM=64 rows x BN=128 cols, BK=32.  256 threads, thread tile 4m x 8n.
#define PAD_A 68
#define PAD_W 132
__global__ __launch_bounds__(256, 4) void ma_energy_kernel(
        const float* __restrict__ enc,
        const float* __restrict__ W,
        const float* __restrict__ ws_in,
        float* __restrict__ epart) {
    __shared__ float As[32][PAD_A];
    __shared__ float Ws[32][PAD_W];
    __shared__ float red[16][PAD_A];

    const int t   = threadIdx.x;
    const int rt  = blockIdx.x;            // 0..1023 row tiles (64 rows each)
    const int nch = blockIdx.y;            // 0..1 (A chunk of 128)
    const size_t R0 = (size_t)rt * 64;
    const int b   = rt >> 5;               // 32 tiles per batch
    const int a0  = nch * 128;

    const int lr = t >> 3;                 // 0..31 (load row)
    const int lk = (t & 7) << 2;           // 0,4,...,28 (load k)

    const float* Ag = enc + (R0 + (size_t)lr) * D_ + lk;
    const float* Wg = W + ((size_t)(a0 + lr)) * D_ + lk;

    const int tm = t & 15;                 // 16 m-groups * 4 rows
    const int tn = t >> 4;                 // 16 n-groups * 8 cols

    float acc[4][8];
    #pragma unroll
    for (int i = 0; i < 4; ++i)
        #pragma unroll
        for (int j = 0; j < 8; ++j) acc[i][j] = 0.f;

    for (int k0 = 0; k0 < D_; k0 += 32) {
        float4 a0v = *(const float4*)(Ag + k0);
        float4 a1v = *(const float4*)(Ag + k0 + 32 * D_);
        float4 w0v = *(const float4*)(Wg + k0);
        float4 w1v = *(const float4*)(Wg + k0 + 32 * D_);
        float4 w2v = *(const float4*)(Wg + k0 + 64 * D_);
        float4 w3v = *(const float4*)(Wg + k0 + 96 * D_);
        __syncthreads();
        As[lk+0][lr] = a0v.x; As[lk+1][lr] = a0v.y;
        As[lk+2][lr] = a0v.z; As[lk+3][lr] = a0v.w;
        As[lk+0][lr+32] = a1v.x; As[lk+1][lr+32] = a1v.y;
        As[lk+2][lr+32] = a1v.z; As[lk+3][lr+32] = a1v.w;
        Ws[lk+0][lr]    = w0v.x; Ws[lk+1][lr]    = w0v.y;
        Ws[lk+2][lr]    = w0v.z; Ws[lk+3][lr]    = w0v.w;
        Ws[lk+0][lr+32] = w1v.x; Ws[lk+1][lr+32] = w1v.y;
        Ws[lk+2][lr+32] = w1v.z; Ws[lk+3][lr+32] = w1v.w;
        Ws[lk+0][lr+64] = w2v.x; Ws[lk+1][lr+64] = w2v.y;
        Ws[lk+2][lr+64] = w2v.z; Ws[lk+3][lr+64] = w2v.w;
        Ws[lk+0][lr+96] = w3v.x; Ws[lk+1][lr+96] = w3v.y;
        Ws[lk+2][lr+96] = w3v.z; Ws[lk+3][lr+96] = w3v.w;
        __syncthreads();
        #pragma unroll
        for (int kk = 0; kk < 32; ++kk) {
            float av[4], wv[8];
            *(float4*)&av[0] = *(const float4*)&As[kk][tm << 2];
            *(float4*)&wv[0] = *(const float4*)&Ws[kk][tn << 3];
            *(float4*)&wv[4] = *(const float4*)&Ws[kk][(tn << 3) + 4];
            #pragma unroll
            for (int i = 0; i < 4; ++i)
                #pragma unroll
                for (int j = 0; j < 8; ++j)
                    acc[i][j] = fmaf(av[i], wv[j], acc[i][j]);
        }
    }

    // epilogue: tanh + weighted sum over this block's 128 a-columns
    const float* weff  = ws_in + WEFF_OFF;
    const float* dterm = ws_in + DEC_OFF + b * A_;
    float p0 = 0.f, p1 = 0.f, p2 = 0.f, p3 = 0.f;
    #pragma unroll
    for (int j = 0; j < 8; ++j) {
        int a = a0 + (tn << 3) + j;
        float wj = weff[a];
        float dj = dterm[a];
        p0 += tanhf(acc[0][j] + dj) * wj;
        p1 += tanhf(acc[1][j] + dj) * wj;
        p2 += tanhf(acc[2][j] + dj) * wj;
        p3 += tanhf(acc[3][j] + dj) * wj;
    }
    __syncthreads();
    red[tn][(tm << 2) + 0] = p0;
    red[tn][(tm << 2) + 1] = p1;
    red[tn][(tm << 2) + 2] = p2;
    red[tn][(tm << 2) + 3] = p3;
    __syncthreads();
    if (t < 64) {
        float e = 0.f;
        #pragma unroll
        for (int q = 0; q < 16; ++q) e += red[q][t];
        epart[(size_t)nch * (B_ * S_) + R0 + t] = e;
    }
}

// ---------------------------------------------------------------------------
// Monotonic recurrence as a stable affine scan:
//   T_j = a_j * T_{j-1} + prev_j,  a_j = clip(1-p_j, 1e-10, 1),  alpha_j = p_j*T_j
// (algebraically identical to p * cumprod * cumsum(prev/cumprod), no under/overflow)
__global__ void ma_scan_kernel(const float* __restrict__ epart,
                               const float* __restrict__ noise,
                               const float* __restrict__ prev,
                               const float* __restrict__ v_bias,
                               const float* __restrict__ r,
                               float* __restrict__ alpha_out) {
    int b = blockIdx.x, t = threadIdx.x;   // 256 threads x 8 elems
    const float bias = v_bias[0] + r[0];
    int base = b * S_ + t * 8;
    float p[8], av[8], bv[8];
    #pragma unroll
    for (int i = 0; i < 8; ++i) {
        float e = epart[base + i] + epart[B_ * S_ + base + i] + bias + noise[base + i];
        float pi = 1.f / (1.f + expf(-e));
        p[i]  = pi;
        av[i] = fmaxf(1.f - pi, 1e-10f);
        bv[i] = prev[base + i];
    }
    // local chunk composition: T_out = Ai*T_in + Bi
    float Ai = 1.f, Bi = 0.f;
    #pragma unroll
    for (int i = 0; i < 8; ++i) { Bi = av[i] * Bi + bv[i]; Ai *= av[i]; }
    // inclusive wave scan (compose prev-lanes then mine)
    int lane = t & 63;
    #pragma unroll
    for (int off = 1; off < 64; off <<= 1) {
        float Ap = __shfl_up(Ai, off, 64);
        float Bp = __shfl_up(Bi, off, 64);
        if (lane >= off) { Bi = Ai * Bp + Bi; Ai = Ai * Ap; }
    }
    __shared__ float wA[4], wB[4];
    int w = t >> 6;
    if (lane == 63) { wA[w] = Ai; wB[w] = Bi; }
    __syncthreads();
    // exclusive composition for this thread
    float Ax = __shfl_up(Ai, 1, 64);
    float Bx = __shfl_up(Bi, 1, 64);
    if (lane == 0) { Ax = 1.f; Bx = 0.f; }
    float PwA = 1.f, PwB = 0.f;
    for (int q = 0; q < w; ++q) { PwB = wA[q] * PwB + wB[q]; PwA *= wA[q]; }
    // T before my chunk (T_0state = 0): apply (PwA,PwB) then (Ax,Bx)
    float T = Ax * PwB + Bx;
    #pragma unroll
    for (int i = 0; i < 8; ++i) {
        T = av[i] * T + bv[i];
        alpha_out[base + i] = p[i] * T;
    }
}

// ---------------------------------------------------------------------------
// context partials over s-chunks of 128
__global__ void ma_ctxpart_kernel(const float* __restrict__ enc,
                                  const float* __restrict__ alpha,
                                  float* __restrict__ cpart) {
    int b = blockIdx.x, sc = blockIdx.y, t = threadIdx.x;   // 256 threads
    const float* e0 = enc + ((size_t)b * S_ + sc * 128) * D_;
    const float* al = alpha + b * S_ + sc * 128;
    float a0 = 0.f, a1 = 0.f;
    for (int s = 0; s < 128; ++s) {
        float avv = al[s];
        a0 = fmaf(e0[(size_t)s * D_ + t], avv, a0);
        a1 = fmaf(e0[(size_t)s * D_ + 256 + t], avv, a1);
    }
    cpart[((size_t)(sc * B_ + b)) * D_ + t]       = a0;
    cpart[((size_t)(sc * B_ + b)) * D_ + 256 + t] = a1;
}

__global__ void ma_ctxreduce_kernel(const float* __restrict__ cpart,
                                    float* __restrict__ ctx) {
    int b = blockIdx.x, t = threadIdx.x;   // 256 threads x 2 d
    #pragma unroll
    for (int h = 0; h < 2; ++h) {
        int d = t + h * 256;
        float s = 0.f;
        #pragma unroll
        for (int q = 0; q < 16; ++q) s += cpart[((size_t)(q * B_ + b)) * D_ + d];
        ctx[b * D_ + d] = s;
    }
}

// ---------------------------------------------------------------------------
extern "C" void kernel_launch(void* const* d_in, const int* in_sizes, int n_in,
                              void* d_out, int out_size, void* d_ws, size_t ws_size,
                              hipStream_t stream) {
    const float* enc    = (const float*)d_in[0];
    const float* dec    = (const float*)d_in[1];
    const float* prev   = (const float*)d_in[2];
    const float* noise  = (const float*)d_in[3];
    const float* W      = (const float*)d_in[4];
    const float* V      = (const float*)d_in[5];
    const float* bvec   = (const float*)d_in[6];
    const float* v_w    = (const float*)d_in[7];
    const float* v_g    = (const float*)d_in[8];
    const float* v_bias = (const float*)d_in[9];
    const float* r      = (const float*)d_in[10];

    float* out = (float*)d_out;             // [0:16384) context, [16384:81920) alpha
    float* ws  = (float*)d_ws;
    float* alpha = out + B_ * D_;

    ma_weff_kernel<<<1, 256, 0, stream>>>(v_w, v_g, ws);
    ma_decterm_kernel<<<B_, 256, 0, stream>>>(dec, V, bvec, ws);
    dim3 ge(1024, 2);
    ma_energy_kernel<<<ge, 256, 0, stream>>>(enc, W, ws, ws + EPART_OFF);
    ma_scan_kernel<<<B_, 256, 0, stream>>>(ws + EPART_OFF, noise, prev, v_bias, r, alpha);
    dim3 gc(B_, 16);
    ma_ctxpart_kernel<<<gc, 256, 0, stream>>>(enc, alpha, ws + CTX_OFF);
    ma_ctxreduce_kernel<<<B_, 256, 0, stream>>>(ws + CTX_OFF, out);
}

// Round 2
// 113.545 us; speedup vs baseline: 2.3380x; 2.3380x over previous
//
#include <hip/hip_runtime.h>
#include <math.h>

// Problem constants
#define B_  32
#define S_  2048
#define D_  512
#define A_  256
#define BS_ (B_ * S_)

// ws layout (float offsets)
#define WEFF_OFF  0            // 256 floats
#define DEC_OFF   256          // B*A = 8192
#define EPART_OFF 8448         // 2 * B*S = 131072
#define CTX_OFF   139520       // 16*B*D = 262144 floats; ALSO reused as W16 (131072 f16)
// W16 (f16 copy of W) lives at CTX_OFF before ctxpart overwrites it (stream-ordered).

typedef _Float16 f16x8 __attribute__((ext_vector_type(8)));
typedef _Float16 half4 __attribute__((ext_vector_type(4)));
typedef float floatx4 __attribute__((ext_vector_type(4)));

// ---------------------------------------------------------------------------
// weight-norm: weff[a] = v_g * v_w[a] / ||v_w||
__global__ void ma_weff_kernel(const float* __restrict__ v_w,
                               const float* __restrict__ v_g,
                               float* __restrict__ ws) {
    int t = threadIdx.x;                 // 256 threads
    float v = v_w[t];
    float sq = v * v;
    #pragma unroll
    for (int off = 32; off > 0; off >>= 1) sq += __shfl_down(sq, off, 64);
    __shared__ float red[4];
    if ((t & 63) == 0) red[t >> 6] = sq;
    __syncthreads();
    float n2 = red[0] + red[1] + red[2] + red[3];
    ws[WEFF_OFF + t] = v_g[0] * v / sqrtf(n2);
}

// ---------------------------------------------------------------------------
// dec_term[b][a] = dot(V[a,:], dec[b,0,:]) + bias[a]
__global__ void ma_decterm_kernel(const float* __restrict__ dec,
                                  const float* __restrict__ V,
                                  const float* __restrict__ bvec,
                                  float* __restrict__ ws) {
    __shared__ float dl[D_];
    int b = blockIdx.x, t = threadIdx.x;  // 256 threads, t == a
    dl[t]       = dec[b * D_ + t];
    dl[t + 256] = dec[b * D_ + 256 + t];
    __syncthreads();
    const float4* Vr = (const float4*)(V + (size_t)t * D_);
    float acc = 0.f;
    #pragma unroll 4
    for (int k = 0; k < D_ / 4; ++k) {
        float4 v4 = Vr[k];
        acc = fmaf(v4.x, dl[4*k+0], acc);
        acc = fmaf(v4.y, dl[4*k+1], acc);
        acc = fmaf(v4.z, dl[4*k+2], acc);
        acc = fmaf(v4.w, dl[4*k+3], acc);
    }
    ws[DEC_OFF + b * A_ + t] = acc + bvec[t];
}

// ---------------------------------------------------------------------------
// W (f32, [A][D]) -> W16 (f16, [A][D])
__global__ void ma_wcvt_kernel(const float* __restrict__ W,
                               _Float16* __restrict__ W16) {
    int i = blockIdx.x * 256 + threadIdx.x;   // grid 128, 4 elems each
    float4 v = ((const float4*)W)[i];
    half4 h;
    h[0] = (_Float16)v.x; h[1] = (_Float16)v.y;
    h[2] = (_Float16)v.z; h[3] = (_Float16)v.w;
    ((half4*)W16)[i] = h;
}

// ---------------------------------------------------------------------------
// Energy via f16 MFMA: per block 128 rows x 128 a-cols x K=512, fused
// tanh + weff reduction -> epart[nch][row].
// 4 waves: (wm, wn) = (wid>>1, wid&1), each 64x64 via 4x4 frags of 16x16x32.
#define LDSTRIDE 40           // f16 units per row (80 B) -> balanced granules
__global__ __launch_bounds__(256, 2) void ma_energy_mfma(
        const float* __restrict__ enc,
        const _Float16* __restrict__ W16,
        const float* __restrict__ ws_in,
        float* __restrict__ epart) {
    __shared__ __align__(16) _Float16 As[128 * LDSTRIDE];
    __shared__ __align__(16) _Float16 Ws[128 * LDSTRIDE];
    __shared__ float red[2][128];

    const int t    = threadIdx.x;
    const int bx   = blockIdx.x;           // 512 row tiles (128 rows each)
    const int nch  = blockIdx.y;           // 0..1 (a-chunk of 128)
    const size_t R0 = (size_t)bx * 128;
    const int batch = bx >> 4;             // 16 tiles per batch (2048/128)
    const int a0   = nch * 128;

    // staging assignments
    const int lrA = t >> 3;                // 0..31
    const int kcA = t & 7;                 // float4 idx within 32-k tile
    const int lrB = t >> 2;                // 0..63
    const int kcB = t & 3;                 // f16x8 idx within 32-k tile
    const float*    Ag = enc + (R0 + (size_t)lrA) * D_ + kcA * 4;
    const _Float16* Bg = W16 + ((size_t)(a0 + lrB)) * D_ + kcB * 8;

    // compute assignments
    const int lane = t & 63, wid = t >> 6;
    const int wm = wid >> 1, wn = wid & 1;
    const int fr = lane & 15, kq = lane >> 4;
    const int baseA = (wm * 64 + fr) * LDSTRIDE + kq * 8;
    const int baseB = (wn * 64 + fr) * LDSTRIDE + kq * 8;

    floatx4 acc[4][4];
    #pragma unroll
    for (int m = 0; m < 4; ++m)
        #pragma unroll
        for (int n = 0; n < 4; ++n) acc[m][n] = (floatx4)0.f;

    float4 pa[4];
    uint4  pb[2];
    #pragma unroll
    for (int i = 0; i < 4; ++i) pa[i] = *(const float4*)(Ag + (size_t)i * 32 * D_);
    #pragma unroll
    for (int i = 0; i < 2; ++i) pb[i] = *(const uint4*)(Bg + (size_t)i * 64 * D_);

    for (int kt = 0; kt < 16; ++kt) {
        __syncthreads();
        // store staged tile to LDS (f32 -> f16 for A)
        #pragma unroll
        for (int i = 0; i < 4; ++i) {
            int row = lrA + 32 * i;
            half4 h;
            h[0] = (_Float16)pa[i].x; h[1] = (_Float16)pa[i].y;
            h[2] = (_Float16)pa[i].z; h[3] = (_Float16)pa[i].w;
            *(half4*)&As[row * LDSTRIDE + kcA * 4] = h;
        }
        #pragma unroll
        for (int i = 0; i < 2; ++i) {
            int row = lrB + 64 * i;
            *(uint4*)&Ws[row * LDSTRIDE + kcB * 8] = pb[i];
        }
        __syncthreads();
        // prefetch next k-tile into regs (hidden under MFMA cluster)
        if (kt < 15) {
            int ko = (kt + 1) * 32;
            #pragma unroll
            for (int i = 0; i < 4; ++i) pa[i] = *(const float4*)(Ag + ko + (size_t)i * 32 * D_);
            #pragma unroll
            for (int i = 0; i < 2; ++i) pb[i] = *(const uint4*)(Bg + ko + (size_t)i * 64 * D_);
        }
        // compute
        f16x8 af[4], bf[4];
        #pragma unroll
        for (int m = 0; m < 4; ++m) af[m] = *(const f16x8*)&As[baseA + m * 16 * LDSTRIDE];
        #pragma unroll
        for (int n = 0; n < 4; ++n) bf[n] = *(const f16x8*)&Ws[baseB + n * 16 * LDSTRIDE];
        #pragma unroll
        for (int m = 0; m < 4; ++m)
            #pragma unroll
            for (int n = 0; n < 4; ++n)
                acc[m][n] = __builtin_amdgcn_mfma_f32_16x16x32_f16(af[m], bf[n], acc[m][n], 0, 0, 0);
    }

    // epilogue: tanh + weighted reduce over this block's 128 a-cols
    const float* weff  = ws_in + WEFF_OFF;
    const float* dterm = ws_in + DEC_OFF + batch * A_;
    float wj[4], dj[4];
    #pragma unroll
    for (int n = 0; n < 4; ++n) {
        int a = a0 + wn * 64 + n * 16 + fr;
        wj[n] = weff[a];
        dj[n] = dterm[a];
    }
    #pragma unroll
    for (int m = 0; m < 4; ++m) {
        #pragma unroll
        for (int r = 0; r < 4; ++r) {
            float v = 0.f;
            #pragma unroll
            for (int n = 0; n < 4; ++n) {
                float x = acc[m][n][r] + dj[n];
                float e = __expf(2.f * x);
                v += (1.f - 2.f / (e + 1.f)) * wj[n];   // tanh(x)
            }
            #pragma unroll
            for (int mask = 1; mask < 16; mask <<= 1)
                v += __shfl_xor(v, mask, 64);
            if (fr == 0)
                red[wn][wm * 64 + m * 16 + (kq << 2) + r] = v;
        }
    }
    __syncthreads();
    if (t < 128)
        epart[(size_t)nch * BS_ + R0 + t] = red[0][t] + red[1][t];
}

// ---------------------------------------------------------------------------
// Monotonic recurrence as a stable affine scan:
//   T_j = a_j * T_{j-1} + prev_j,  a_j = clip(1-p_j, 1e-10, 1),  alpha_j = p_j*T_j
__global__ void ma_scan_kernel(const float* __restrict__ epart,
                               const float* __restrict__ noise,
                               const float* __restrict__ prev,
                               const float* __restrict__ v_bias,
                               const float* __restrict__ r,
                               float* __restrict__ alpha_out) {
    int b = blockIdx.x, t = threadIdx.x;   // 256 threads x 8 elems
    const float bias = v_bias[0] + r[0];
    int base = b * S_ + t * 8;
    float p[8], av[8], bv[8];
    #pragma unroll
    for (int i = 0; i < 8; ++i) {
        float e = epart[base + i] + epart[BS_ + base + i] + bias + noise[base + i];
        float pi = 1.f / (1.f + expf(-e));
        p[i]  = pi;
        av[i] = fmaxf(1.f - pi, 1e-10f);
        bv[i] = prev[base + i];
    }
    float Ai = 1.f, Bi = 0.f;
    #pragma unroll
    for (int i = 0; i < 8; ++i) { Bi = av[i] * Bi + bv[i]; Ai *= av[i]; }
    int lane = t & 63;
    #pragma unroll
    for (int off = 1; off < 64; off <<= 1) {
        float Ap = __shfl_up(Ai, off, 64);
        float Bp = __shfl_up(Bi, off, 64);
        if (lane >= off) { Bi = Ai * Bp + Bi; Ai = Ai * Ap; }
    }
    __shared__ float wA[4], wB[4];
    int w = t >> 6;
    if (lane == 63) { wA[w] = Ai; wB[w] = Bi; }
    __syncthreads();
    float Ax = __shfl_up(Ai, 1, 64);
    float Bx = __shfl_up(Bi, 1, 64);
    if (lane == 0) { Ax = 1.f; Bx = 0.f; }
    float PwA = 1.f, PwB = 0.f;
    for (int q = 0; q < w; ++q) { PwB = wA[q] * PwB + wB[q]; PwA *= wA[q]; }
    float T = Ax * PwB + Bx;
    #pragma unroll
    for (int i = 0; i < 8; ++i) {
        T = av[i] * T + bv[i];
        alpha_out[base + i] = p[i] * T;
    }
}

// ---------------------------------------------------------------------------
// context partials over s-chunks of 128
__global__ void ma_ctxpart_kernel(const float* __restrict__ enc,
                                  const float* __restrict__ alpha,
                                  float* __restrict__ cpart) {
    int b = blockIdx.x, sc = blockIdx.y, t = threadIdx.x;   // 256 threads
    const float* e0 = enc + ((size_t)b * S_ + sc * 128) * D_;
    const float* al = alpha + b * S_ + sc * 128;
    float a0 = 0.f, a1 = 0.f;
    for (int s = 0; s < 128; ++s) {
        float avv = al[s];
        a0 = fmaf(e0[(size_t)s * D_ + t], avv, a0);
        a1 = fmaf(e0[(size_t)s * D_ + 256 + t], avv, a1);
    }
    cpart[((size_t)(sc * B_ + b)) * D_ + t]       = a0;
    cpart[((size_t)(sc * B_ + b)) * D_ + 256 + t] = a1;
}

__global__ void ma_ctxreduce_kernel(const float* __restrict__ cpart,
                                    float* __restrict__ ctx) {
    int b = blockIdx.x, t = threadIdx.x;
    #pragma unroll
    for (int h = 0; h < 2; ++h) {
        int d = t + h * 256;
        float s = 0.f;
        #pragma unroll
        for (int q = 0; q < 16; ++q) s += cpart[((size_t)(q * B_ + b)) * D_ + d];
        ctx[b * D_ + d] = s;
    }
}

// ---------------------------------------------------------------------------
extern "C" void kernel_launch(void* const* d_in, const int* in_sizes, int n_in,
                              void* d_out, int out_size, void* d_ws, size_t ws_size,
                              hipStream_t stream) {
    const float* enc    = (const float*)d_in[0];
    const float* dec    = (const float*)d_in[1];
    const float* prev   = (const float*)d_in[2];
    const float* noise  = (const float*)d_in[3];
    const float* W      = (const float*)d_in[4];
    const float* V      = (const float*)d_in[5];
    const float* bvec   = (const float*)d_in[6];
    const float* v_w    = (const float*)d_in[7];
    const float* v_g    = (const float*)d_in[8];
    const float* v_bias = (const float*)d_in[9];
    const float* r      = (const float*)d_in[10];

    float* out = (float*)d_out;             // [0:16384) context, [16384:81920) alpha
    float* ws  = (float*)d_ws;
    float* alpha = out + B_ * D_;
    _Float16* W16 = (_Float16*)(ws + CTX_OFF);   // region reused by cpart later

    ma_weff_kernel<<<1, 256, 0, stream>>>(v_w, v_g, ws);
    ma_decterm_kernel<<<B_, 256, 0, stream>>>(dec, V, bvec, ws);
    ma_wcvt_kernel<<<128, 256, 0, stream>>>(W, W16);
    dim3 ge(512, 2);
    ma_energy_mfma<<<ge, 256, 0, stream>>>(enc, W16, ws, ws + EPART_OFF);
    ma_scan_kernel<<<B_, 256, 0, stream>>>(ws + EPART_OFF, noise, prev, v_bias, r, alpha);
    dim3 gc(B_, 16);
    ma_ctxpart_kernel<<<gc, 256, 0, stream>>>(enc, alpha, ws + CTX_OFF);
    ma_ctxreduce_kernel<<<B_, 256, 0, stream>>>(ws + CTX_OFF, out);
}

// Round 3
// 95.421 us; speedup vs baseline: 2.7821x; 1.1899x over previous
//
#include <hip/hip_runtime.h>
#include <math.h>

// Problem constants
#define B_  32
#define S_  2048
#define D_  512
#define A_  256
#define BS_ (B_ * S_)

// ws layout (float offsets)
#define WEFF_OFF  0                   // 256 floats
#define DEC_OFF   256                 // B*A = 8192
#define EPART_OFF 8448                // B*S = 65536 floats (single energy array)
#define CTX_OFF   (8448 + BS_)        // 16*B*D = 262144 floats; first reused as W16 (f16)

typedef _Float16 f16x8 __attribute__((ext_vector_type(8)));
typedef _Float16 half4 __attribute__((ext_vector_type(4)));
typedef float floatx4 __attribute__((ext_vector_type(4)));

// ---------------------------------------------------------------------------
// Merged prep: block 0 = weff, blocks 1..32 = dec_term, blocks 33..160 = W->f16
__global__ void ma_prep_kernel(const float* __restrict__ v_w,
                               const float* __restrict__ v_g,
                               const float* __restrict__ dec,
                               const float* __restrict__ V,
                               const float* __restrict__ bvec,
                               const float* __restrict__ W,
                               _Float16* __restrict__ W16,
                               float* __restrict__ ws) {
    __shared__ float sh[D_];
    const int bid = blockIdx.x, t = threadIdx.x;
    if (bid == 0) {
        // weight-norm: weff[a] = v_g * v_w[a] / ||v_w||
        float v = v_w[t];
        float sq = v * v;
        #pragma unroll
        for (int off = 32; off > 0; off >>= 1) sq += __shfl_down(sq, off, 64);
        if ((t & 63) == 0) sh[t >> 6] = sq;
        __syncthreads();
        float n2 = sh[0] + sh[1] + sh[2] + sh[3];
        ws[WEFF_OFF + t] = v_g[0] * v / sqrtf(n2);
    } else if (bid <= B_) {
        // dec_term[b][a] = dot(V[a,:], dec[b,:]) + bvec[a]
        const int b = bid - 1;
        sh[t]       = dec[b * D_ + t];
        sh[t + 256] = dec[b * D_ + 256 + t];
        __syncthreads();
        const float4* Vr = (const float4*)(V + (size_t)t * D_);
        float acc = 0.f;
        #pragma unroll 4
        for (int k = 0; k < D_ / 4; ++k) {
            float4 v4 = Vr[k];
            acc = fmaf(v4.x, sh[4*k+0], acc);
            acc = fmaf(v4.y, sh[4*k+1], acc);
            acc = fmaf(v4.z, sh[4*k+2], acc);
            acc = fmaf(v4.w, sh[4*k+3], acc);
        }
        ws[DEC_OFF + b * A_ + t] = acc + bvec[t];
    } else {
        // W (f32) -> W16 (f16), 32768 float4 groups total
        int i = (bid - (B_ + 1)) * 256 + t;
        float4 v = ((const float4*)W)[i];
        half4 h;
        h[0] = (_Float16)v.x; h[1] = (_Float16)v.y;
        h[2] = (_Float16)v.z; h[3] = (_Float16)v.w;
        ((half4*)W16)[i] = h;
    }
}

// ---------------------------------------------------------------------------
// Energy: block = 64 rows x full A=256, K=512. 4 waves, each 64x64 (4x4 frags
// of 16x16x32 f16). A staged in LDS (f16, double-buffered); B read per-wave
// directly from global (W16 is 256 KB -> L2-resident). Fused tanh + weff
// reduction -> energy[row].
#define LDST 40           // f16 units per LDS row (80 B) -> balanced banks
__global__ void ma_energy_mfma(
        const float* __restrict__ enc,
        const _Float16* __restrict__ W16,
        const float* __restrict__ ws_in,
        float* __restrict__ energy) {
    __shared__ __align__(16) _Float16 As[2][64 * LDST];
    __shared__ float red[4][64];

    const int t  = threadIdx.x;
    const int bx = blockIdx.x;             // 1024 tiles of 64 rows
    const size_t R0 = (size_t)bx * 64;
    const int batch = bx >> 5;             // 32 tiles per batch

    // A staging: thread loads 8 f32 of one row per k-tile
    const int lr = t >> 2;                 // 0..63
    const int kc = (t & 3) * 8;            // f32 offset within 32-k tile
    const float* Ag = enc + (R0 + (size_t)lr) * D_ + kc;

    // compute assignment
    const int lane = t & 63, wn = t >> 6;  // wave n-chunk: a0 = wn*64
    const int fr = lane & 15, kq = lane >> 4;
    const _Float16* Bg = W16 + (size_t)(wn * 64 + fr) * D_ + kq * 8;

    floatx4 acc[4][4];
    #pragma unroll
    for (int m = 0; m < 4; ++m)
        #pragma unroll
        for (int n = 0; n < 4; ++n) acc[m][n] = (floatx4)0.f;

    // prologue: stage tile 0, prefetch tile 1 into regs
    float4 pa0 = *(const float4*)(Ag);
    float4 pa1 = *(const float4*)(Ag + 4);
    {
        f16x8 h;
        h[0] = (_Float16)pa0.x; h[1] = (_Float16)pa0.y;
        h[2] = (_Float16)pa0.z; h[3] = (_Float16)pa0.w;
        h[4] = (_Float16)pa1.x; h[5] = (_Float16)pa1.y;
        h[6] = (_Float16)pa1.z; h[7] = (_Float16)pa1.w;
        *(f16x8*)&As[0][lr * LDST + kc] = h;
    }
    pa0 = *(const float4*)(Ag + 32);
    pa1 = *(const float4*)(Ag + 36);
    __syncthreads();

    for (int kt = 0; kt < 16; ++kt) {
        const int cur = kt & 1;
        // B frags for this k-tile, straight from L2
        f16x8 bf[4];
        #pragma unroll
        for (int n = 0; n < 4; ++n)
            bf[n] = *(const f16x8*)(Bg + (size_t)(n * 16) * D_ + kt * 32);
        // stage tile kt+1 (regs loaded last iter) into the other buffer
        if (kt < 15) {
            f16x8 h;
            h[0] = (_Float16)pa0.x; h[1] = (_Float16)pa0.y;
            h[2] = (_Float16)pa0.z; h[3] = (_Float16)pa0.w;
            h[4] = (_Float16)pa1.x; h[5] = (_Float16)pa1.y;
            h[6] = (_Float16)pa1.z; h[7] = (_Float16)pa1.w;
            *(f16x8*)&As[cur ^ 1][lr * LDST + kc] = h;
        }
        // prefetch tile kt+2 raw f32
        if (kt < 14) {
            pa0 = *(const float4*)(Ag + (kt + 2) * 32);
            pa1 = *(const float4*)(Ag + (kt + 2) * 32 + 4);
        }
        // A frags from LDS
        f16x8 af[4];
        #pragma unroll
        for (int m = 0; m < 4; ++m)
            af[m] = *(const f16x8*)&As[cur][(m * 16 + fr) * LDST + kq * 8];
        // MFMA cluster
        #pragma unroll
        for (int m = 0; m < 4; ++m)
            #pragma unroll
            for (int n = 0; n < 4; ++n)
                acc[m][n] = __builtin_amdgcn_mfma_f32_16x16x32_f16(af[m], bf[n], acc[m][n], 0, 0, 0);
        __syncthreads();
    }

    // epilogue: tanh + weighted reduce over all 256 a-cols
    const float* weff  = ws_in + WEFF_OFF;
    const float* dterm = ws_in + DEC_OFF + batch * A_;
    float wj[4], dj[4];
    #pragma unroll
    for (int n = 0; n < 4; ++n) {
        int a = wn * 64 + n * 16 + fr;
        wj[n] = weff[a];
        dj[n] = dterm[a];
    }
    #pragma unroll
    for (int m = 0; m < 4; ++m) {
        #pragma unroll
        for (int r = 0; r < 4; ++r) {
            float v = 0.f;
            #pragma unroll
            for (int n = 0; n < 4; ++n) {
                float x = acc[m][n][r] + dj[n];
                float e = __expf(2.f * x);
                v += (1.f - 2.f / (e + 1.f)) * wj[n];   // tanh(x)
            }
            #pragma unroll
            for (int mask = 1; mask < 16; mask <<= 1)
                v += __shfl_xor(v, mask, 64);
            if (fr == 0)
                red[wn][m * 16 + (kq << 2) + r] = v;
        }
    }
    __syncthreads();
    if (t < 64)
        energy[R0 + t] = red[0][t] + red[1][t] + red[2][t] + red[3][t];
}

// ---------------------------------------------------------------------------
// Monotonic recurrence as a stable affine scan:
//   T_j = a_j * T_{j-1} + prev_j,  a_j = clip(1-p_j, 1e-10, 1),  alpha_j = p_j*T_j
__global__ void ma_scan_kernel(const float* __restrict__ energy,
                               const float* __restrict__ noise,
                               const float* __restrict__ prev,
                               const float* __restrict__ v_bias,
                               const float* __restrict__ r,
                               float* __restrict__ alpha_out) {
    int b = blockIdx.x, t = threadIdx.x;   // 256 threads x 8 elems
    const float bias = v_bias[0] + r[0];
    int base = b * S_ + t * 8;
    float p[8], av[8], bv[8];
    #pragma unroll
    for (int i = 0; i < 8; ++i) {
        float e = energy[base + i] + bias + noise[base + i];
        float pi = 1.f / (1.f + expf(-e));
        p[i]  = pi;
        av[i] = fmaxf(1.f - pi, 1e-10f);
        bv[i] = prev[base + i];
    }
    float Ai = 1.f, Bi = 0.f;
    #pragma unroll
    for (int i = 0; i < 8; ++i) { Bi = av[i] * Bi + bv[i]; Ai *= av[i]; }
    int lane = t & 63;
    #pragma unroll
    for (int off = 1; off < 64; off <<= 1) {
        float Ap = __shfl_up(Ai, off, 64);
        float Bp = __shfl_up(Bi, off, 64);
        if (lane >= off) { Bi = Ai * Bp + Bi; Ai = Ai * Ap; }
    }
    __shared__ float wA[4], wB[4];
    int w = t >> 6;
    if (lane == 63) { wA[w] = Ai; wB[w] = Bi; }
    __syncthreads();
    float Ax = __shfl_up(Ai, 1, 64);
    float Bx = __shfl_up(Bi, 1, 64);
    if (lane == 0) { Ax = 1.f; Bx = 0.f; }
    float PwA = 1.f, PwB = 0.f;
    for (int q = 0; q < w; ++q) { PwB = wA[q] * PwB + wB[q]; PwA *= wA[q]; }
    float T = Ax * PwB + Bx;
    #pragma unroll
    for (int i = 0; i < 8; ++i) {
        T = av[i] * T + bv[i];
        alpha_out[base + i] = p[i] * T;
    }
}

// ---------------------------------------------------------------------------
// context partials over s-chunks of 128
__global__ void ma_ctxpart_kernel(const float* __restrict__ enc,
                                  const float* __restrict__ alpha,
                                  float* __restrict__ cpart) {
    int b = blockIdx.x, sc = blockIdx.y, t = threadIdx.x;   // 256 threads
    const float* e0 = enc + ((size_t)b * S_ + sc * 128) * D_;
    const float* al = alpha + b * S_ + sc * 128;
    float a0 = 0.f, a1 = 0.f;
    for (int s = 0; s < 128; ++s) {
        float avv = al[s];
        a0 = fmaf(e0[(size_t)s * D_ + t], avv, a0);
        a1 = fmaf(e0[(size_t)s * D_ + 256 + t], avv, a1);
    }
    cpart[((size_t)(sc * B_ + b)) * D_ + t]       = a0;
    cpart[((size_t)(sc * B_ + b)) * D_ + 256 + t] = a1;
}

__global__ void ma_ctxreduce_kernel(const float* __restrict__ cpart,
                                    float* __restrict__ ctx) {
    int b = blockIdx.x, t = threadIdx.x;
    #pragma unroll
    for (int h = 0; h < 2; ++h) {
        int d = t + h * 256;
        float s = 0.f;
        #pragma unroll
        for (int q = 0; q < 16; ++q) s += cpart[((size_t)(q * B_ + b)) * D_ + d];
        ctx[b * D_ + d] = s;
    }
}

// ---------------------------------------------------------------------------
extern "C" void kernel_launch(void* const* d_in, const int* in_sizes, int n_in,
                              void* d_out, int out_size, void* d_ws, size_t ws_size,
                              hipStream_t stream) {
    const float* enc    = (const float*)d_in[0];
    const float* dec    = (const float*)d_in[1];
    const float* prev   = (const float*)d_in[2];
    const float* noise  = (const float*)d_in[3];
    const float* W      = (const float*)d_in[4];
    const float* V      = (const float*)d_in[5];
    const float* bvec   = (const float*)d_in[6];
    const float* v_w    = (const float*)d_in[7];
    const float* v_g    = (const float*)d_in[8];
    const float* v_bias = (const float*)d_in[9];
    const float* r      = (const float*)d_in[10];

    float* out = (float*)d_out;             // [0:16384) context, [16384:81920) alpha
    float* ws  = (float*)d_ws;
    float* alpha = out + B_ * D_;
    _Float16* W16 = (_Float16*)(ws + CTX_OFF);   // region reused by cpart later

    ma_prep_kernel<<<1 + B_ + 128, 256, 0, stream>>>(v_w, v_g, dec, V, bvec, W, W16, ws);
    ma_energy_mfma<<<1024, 256, 0, stream>>>(enc, W16, ws, ws + EPART_OFF);
    ma_scan_kernel<<<B_, 256, 0, stream>>>(ws + EPART_OFF, noise, prev, v_bias, r, alpha);
    dim3 gc(B_, 16);
    ma_ctxpart_kernel<<<gc, 256, 0, stream>>>(enc, alpha, ws + CTX_OFF);
    ma_ctxreduce_kernel<<<B_, 256, 0, stream>>>(ws + CTX_OFF, out);
}

// Round 4
// 85.943 us; speedup vs baseline: 3.0889x; 1.1103x over previous
//
#include <hip/hip_runtime.h>
#include <math.h>

// Problem constants
#define B_  32
#define S_  2048
#define D_  512
#define A_  256
#define BS_ (B_ * S_)

// ws layout (float offsets)
#define WEFF_OFF  0                   // 256 floats
#define DEC_OFF   256                 // B*A = 8192
#define EPART_OFF 8448                // B*S = 65536 floats
#define CTX_OFF   (8448 + BS_)        // 16*B*D = 262144 floats; first reused as W16 (f16)

typedef _Float16 f16x8 __attribute__((ext_vector_type(8)));
typedef _Float16 half4 __attribute__((ext_vector_type(4)));
typedef float floatx4 __attribute__((ext_vector_type(4)));

__device__ __forceinline__ void glds16(const void* g, void* l) {
    __builtin_amdgcn_global_load_lds(
        (const __attribute__((address_space(1))) void*)g,
        (__attribute__((address_space(3))) void*)l, 16, 0, 0);
}

// ---------------------------------------------------------------------------
// Merged prep: block 0 = weff, blocks 1..32 = dec_term, blocks 33..160 = W->f16
__global__ void ma_prep_kernel(const float* __restrict__ v_w,
                               const float* __restrict__ v_g,
                               const float* __restrict__ dec,
                               const float* __restrict__ V,
                               const float* __restrict__ bvec,
                               const float* __restrict__ W,
                               _Float16* __restrict__ W16,
                               float* __restrict__ ws) {
    __shared__ float sh[D_];
    const int bid = blockIdx.x, t = threadIdx.x;
    if (bid == 0) {
        float v = v_w[t];
        float sq = v * v;
        #pragma unroll
        for (int off = 32; off > 0; off >>= 1) sq += __shfl_down(sq, off, 64);
        if ((t & 63) == 0) sh[t >> 6] = sq;
        __syncthreads();
        float n2 = sh[0] + sh[1] + sh[2] + sh[3];
        ws[WEFF_OFF + t] = v_g[0] * v / sqrtf(n2);
    } else if (bid <= B_) {
        const int b = bid - 1;
        sh[t]       = dec[b * D_ + t];
        sh[t + 256] = dec[b * D_ + 256 + t];
        __syncthreads();
        const float4* Vr = (const float4*)(V + (size_t)t * D_);
        float acc = 0.f;
        #pragma unroll 4
        for (int k = 0; k < D_ / 4; ++k) {
            float4 v4 = Vr[k];
            acc = fmaf(v4.x, sh[4*k+0], acc);
            acc = fmaf(v4.y, sh[4*k+1], acc);
            acc = fmaf(v4.z, sh[4*k+2], acc);
            acc = fmaf(v4.w, sh[4*k+3], acc);
        }
        ws[DEC_OFF + b * A_ + t] = acc + bvec[t];
    } else {
        int i = (bid - (B_ + 1)) * 256 + t;
        float4 v = ((const float4*)W)[i];
        half4 h;
        h[0] = (_Float16)v.x; h[1] = (_Float16)v.y;
        h[2] = (_Float16)v.z; h[3] = (_Float16)v.w;
        ((half4*)W16)[i] = h;
    }
}

// ---------------------------------------------------------------------------
// Energy: block = 128 rows x 256 a-cols, K=512. 8 waves (2 wm x 4 wn), each
// 64x64 via 4x4 frags of 16x16x32 f16. A reg-staged f32->f16 into LDS;
// B staged via global_load_lds (zero-reg). Double-buffered. Fused tanh+weff.
#define LDSTA 40          // f16 per A row (80 B)
__global__ __launch_bounds__(512) void ma_energy_mfma(
        const float* __restrict__ enc,
        const _Float16* __restrict__ W16,
        const float* __restrict__ ws_in,
        float* __restrict__ energy) {
    __shared__ __align__(16) _Float16 As[2][128 * LDSTA];   // 20480 B
    __shared__ __align__(16) _Float16 Bs[2][256 * 32];      // 32768 B
    __shared__ float red[4][128];                           //  2048 B

    const int t  = threadIdx.x;
    const int bx = blockIdx.x;             // 512 tiles of 128 rows
    const size_t R0 = (size_t)bx * 128;
    const int batch = bx >> 4;             // 16 tiles per batch

    // A staging: thread loads 8 f32 of one row per k-tile
    const int lr = t >> 2;                 // 0..127
    const int kc = (t & 3) * 8;            // f32 offset within 32-k tile
    const float* Ag = enc + (R0 + (size_t)lr) * D_ + kc;

    const int lane = t & 63, wid = t >> 6;
    const int wm = wid >> 2, wn = wid & 3;
    const int fr = lane & 15, kq = lane >> 4;

    // B staging: wave wid stages rows [wid*32, wid*32+32), 2 glds/iter
    const _Float16* Bg0 = W16 + (size_t)(wid * 32 + (lane >> 2)) * D_ + (lane & 3) * 8;
    const _Float16* Bg1 = Bg0 + (size_t)16 * D_;
    const int bdst0 = (wid * 32) * 32;     // f16 offset in Bs buffer
    const int bdst1 = (wid * 32 + 16) * 32;

    floatx4 acc[4][4];
    #pragma unroll
    for (int m = 0; m < 4; ++m)
        #pragma unroll
        for (int n = 0; n < 4; ++n) acc[m][n] = (floatx4)0.f;

    // prologue: stage tile 0 (B via glds, A via regs), prefetch A tile 1
    glds16(Bg0, &Bs[0][bdst0]);
    glds16(Bg1, &Bs[0][bdst1]);
    float4 a0 = *(const float4*)(Ag);
    float4 a1 = *(const float4*)(Ag + 4);
    {
        f16x8 h;
        h[0] = (_Float16)a0.x; h[1] = (_Float16)a0.y;
        h[2] = (_Float16)a0.z; h[3] = (_Float16)a0.w;
        h[4] = (_Float16)a1.x; h[5] = (_Float16)a1.y;
        h[6] = (_Float16)a1.z; h[7] = (_Float16)a1.w;
        *(f16x8*)&As[0][lr * LDSTA + kc] = h;
    }
    a0 = *(const float4*)(Ag + 32);
    a1 = *(const float4*)(Ag + 36);
    __syncthreads();

    for (int kt = 0; kt < 16; ++kt) {
        const int cur = kt & 1;
        // issue next B tile (direct to LDS, no regs)
        if (kt < 15) {
            glds16(Bg0 + (kt + 1) * 32, &Bs[cur ^ 1][bdst0]);
            glds16(Bg1 + (kt + 1) * 32, &Bs[cur ^ 1][bdst1]);
        }
        // frags for this tile
        f16x8 af[4], bf[4];
        #pragma unroll
        for (int m = 0; m < 4; ++m)
            af[m] = *(const f16x8*)&As[cur][(wm * 64 + m * 16 + fr) * LDSTA + kq * 8];
        #pragma unroll
        for (int n = 0; n < 4; ++n)
            bf[n] = *(const f16x8*)&Bs[cur][(wn * 64 + n * 16 + fr) * 32 + kq * 8];
        // write prefetched A (kt+1) into other buffer
        if (kt < 15) {
            f16x8 h;
            h[0] = (_Float16)a0.x; h[1] = (_Float16)a0.y;
            h[2] = (_Float16)a0.z; h[3] = (_Float16)a0.w;
            h[4] = (_Float16)a1.x; h[5] = (_Float16)a1.y;
            h[6] = (_Float16)a1.z; h[7] = (_Float16)a1.w;
            *(f16x8*)&As[cur ^ 1][lr * LDSTA + kc] = h;
        }
        // prefetch A (kt+2) raw f32
        if (kt < 14) {
            a0 = *(const float4*)(Ag + (kt + 2) * 32);
            a1 = *(const float4*)(Ag + (kt + 2) * 32 + 4);
        }
        // MFMA cluster
        #pragma unroll
        for (int m = 0; m < 4; ++m)
            #pragma unroll
            for (int n = 0; n < 4; ++n)
                acc[m][n] = __builtin_amdgcn_mfma_f32_16x16x32_f16(af[m], bf[n], acc[m][n], 0, 0, 0);
        __syncthreads();
    }

    // epilogue: tanh + weighted reduce over all 256 a-cols
    const float* weff  = ws_in + WEFF_OFF;
    const float* dterm = ws_in + DEC_OFF + batch * A_;
    float wj[4], dj[4];
    #pragma unroll
    for (int n = 0; n < 4; ++n) {
        int a = wn * 64 + n * 16 + fr;
        wj[n] = weff[a];
        dj[n] = dterm[a];
    }
    #pragma unroll
    for (int m = 0; m < 4; ++m) {
        #pragma unroll
        for (int r = 0; r < 4; ++r) {
            float v = 0.f;
            #pragma unroll
            for (int n = 0; n < 4; ++n) {
                float x = acc[m][n][r] + dj[n];
                float e = __expf(2.f * x);
                v += (1.f - 2.f / (e + 1.f)) * wj[n];   // tanh(x)
            }
            #pragma unroll
            for (int mask = 1; mask < 16; mask <<= 1)
                v += __shfl_xor(v, mask, 64);
            if (fr == 0)
                red[wn][wm * 64 + m * 16 + (kq << 2) + r] = v;
        }
    }
    __syncthreads();
    if (t < 128)
        energy[R0 + t] = red[0][t] + red[1][t] + red[2][t] + red[3][t];
}

// ---------------------------------------------------------------------------
// Monotonic recurrence as a stable affine scan:
//   T_j = a_j * T_{j-1} + prev_j,  a_j = clip(1-p_j, 1e-10, 1),  alpha_j = p_j*T_j
__global__ void ma_scan_kernel(const float* __restrict__ energy,
                               const float* __restrict__ noise,
                               const float* __restrict__ prev,
                               const float* __restrict__ v_bias,
                               const float* __restrict__ r,
                               float* __restrict__ alpha_out) {
    int b = blockIdx.x, t = threadIdx.x;   // 256 threads x 8 elems
    const float bias = v_bias[0] + r[0];
    int base = b * S_ + t * 8;
    float p[8], av[8], bv[8];
    #pragma unroll
    for (int i = 0; i < 8; ++i) {
        float e = energy[base + i] + bias + noise[base + i];
        float pi = 1.f / (1.f + expf(-e));
        p[i]  = pi;
        av[i] = fmaxf(1.f - pi, 1e-10f);
        bv[i] = prev[base + i];
    }
    float Ai = 1.f, Bi = 0.f;
    #pragma unroll
    for (int i = 0; i < 8; ++i) { Bi = av[i] * Bi + bv[i]; Ai *= av[i]; }
    int lane = t & 63;
    #pragma unroll
    for (int off = 1; off < 64; off <<= 1) {
        float Ap = __shfl_up(Ai, off, 64);
        float Bp = __shfl_up(Bi, off, 64);
        if (lane >= off) { Bi = Ai * Bp + Bi; Ai = Ai * Ap; }
    }
    __shared__ float wA[4], wB[4];
    int w = t >> 6;
    if (lane == 63) { wA[w] = Ai; wB[w] = Bi; }
    __syncthreads();
    float Ax = __shfl_up(Ai, 1, 64);
    float Bx = __shfl_up(Bi, 1, 64);
    if (lane == 0) { Ax = 1.f; Bx = 0.f; }
    float PwA = 1.f, PwB = 0.f;
    for (int q = 0; q < w; ++q) { PwB = wA[q] * PwB + wB[q]; PwA *= wA[q]; }
    float T = Ax * PwB + Bx;
    #pragma unroll
    for (int i = 0; i < 8; ++i) {
        T = av[i] * T + bv[i];
        alpha_out[base + i] = p[i] * T;
    }
}

// ---------------------------------------------------------------------------
// context partials over s-chunks of 128
__global__ void ma_ctxpart_kernel(const float* __restrict__ enc,
                                  const float* __restrict__ alpha,
                                  float* __restrict__ cpart) {
    int b = blockIdx.x, sc = blockIdx.y, t = threadIdx.x;   // 256 threads
    const float* e0 = enc + ((size_t)b * S_ + sc * 128) * D_;
    const float* al = alpha + b * S_ + sc * 128;
    float a0 = 0.f, a1 = 0.f;
    for (int s = 0; s < 128; ++s) {
        float avv = al[s];
        a0 = fmaf(e0[(size_t)s * D_ + t], avv, a0);
        a1 = fmaf(e0[(size_t)s * D_ + 256 + t], avv, a1);
    }
    cpart[((size_t)(sc * B_ + b)) * D_ + t]       = a0;
    cpart[((size_t)(sc * B_ + b)) * D_ + 256 + t] = a1;
}

__global__ void ma_ctxreduce_kernel(const float* __restrict__ cpart,
                                    float* __restrict__ ctx) {
    int b = blockIdx.x, t = threadIdx.x;
    #pragma unroll
    for (int h = 0; h < 2; ++h) {
        int d = t + h * 256;
        float s = 0.f;
        #pragma unroll
        for (int q = 0; q < 16; ++q) s += cpart[((size_t)(q * B_ + b)) * D_ + d];
        ctx[b * D_ + d] = s;
    }
}

// ---------------------------------------------------------------------------
extern "C" void kernel_launch(void* const* d_in, const int* in_sizes, int n_in,
                              void* d_out, int out_size, void* d_ws, size_t ws_size,
                              hipStream_t stream) {
    const float* enc    = (const float*)d_in[0];
    const float* dec    = (const float*)d_in[1];
    const float* prev   = (const float*)d_in[2];
    const float* noise  = (const float*)d_in[3];
    const float* W      = (const float*)d_in[4];
    const float* V      = (const float*)d_in[5];
    const float* bvec   = (const float*)d_in[6];
    const float* v_w    = (const float*)d_in[7];
    const float* v_g    = (const float*)d_in[8];
    const float* v_bias = (const float*)d_in[9];
    const float* r      = (const float*)d_in[10];

    float* out = (float*)d_out;             // [0:16384) context, [16384:81920) alpha
    float* ws  = (float*)d_ws;
    float* alpha = out + B_ * D_;
    _Float16* W16 = (_Float16*)(ws + CTX_OFF);   // region reused by cpart later

    ma_prep_kernel<<<1 + B_ + 128, 256, 0, stream>>>(v_w, v_g, dec, V, bvec, W, W16, ws);
    ma_energy_mfma<<<512, 512, 0, stream>>>(enc, W16, ws, ws + EPART_OFF);
    ma_scan_kernel<<<B_, 256, 0, stream>>>(ws + EPART_OFF, noise, prev, v_bias, r, alpha);
    dim3 gc(B_, 16);
    ma_ctxpart_kernel<<<gc, 256, 0, stream>>>(enc, alpha, ws + CTX_OFF);
    ma_ctxreduce_kernel<<<B_, 256, 0, stream>>>(ws + CTX_OFF, out);
}